// Round 12
// baseline (394.354 us; speedup 1.0000x reference)
//
#include <hip/hip_runtime.h>
#include <hip/hip_bf16.h>

typedef unsigned short u16;
using short8  = __attribute__((ext_vector_type(8))) short;
using ushort8 = __attribute__((ext_vector_type(8))) unsigned short;
using float4v = __attribute__((ext_vector_type(4))) float;

#define N_POL  100000
#define N_TICK 20000
#define NNODE  120000
#define NEDGE  1000000
#define NTILE  1875     // NNODE / 64
#define GB2    512      // fused_gemm grid: 2 blocks/CU at 64KB LDS
// EMB=128, HID=256, OUT=128

static __device__ __forceinline__ float b2f(u16 u) {
    return __uint_as_float(((unsigned)u) << 16);
}
static __device__ __forceinline__ u16 f2b(float f) {
    unsigned u = __float_as_uint(f);
    unsigned r = (u + 0x7FFFu + ((u >> 16) & 1u)) >> 16;
    return (u16)r;
}
static __device__ __forceinline__ float lde(const void* p, size_t i, int f32) {
    return f32 ? ((const float*)p)[i] : b2f(((const u16*)p)[i]);
}

// MFMA B-fragment address for K=256, N=256 packed weights (verified R7):
// element (k,n) -> ((n/16)*8 + k/32)*512 + (((k>>3)&3)*16 + (n&15))*8 + (k&7)
static __device__ __forceinline__ size_t frag_addr(int k, int n) {
    return ((size_t)((n >> 4) * 8 + (k >> 5)) * 64 + (((k >> 3) & 3) * 16 + (n & 15))) * 8
           + (k & 7);
}

// 16B global->LDS DMA (wave-uniform LDS base; HW adds lane*16)
static __device__ __forceinline__ void gload_lds16(const u16* g, u16* l) {
    __builtin_amdgcn_global_load_lds(
        (const __attribute__((address_space(1))) void*)g,
        (__attribute__((address_space(3))) void*)l, 16, 0, 0);
}

// Stage one 64-row A tile (chunks 0-15 agg, 16-31 Xb) into dst (32KB), XOR-swizzled
// source so LDS stays linear (rule #21). Each DMA instr: 16 fully-used 64B lines.
static __device__ __forceinline__ void stage_tile(const u16* __restrict__ agg,
                                                  const u16* __restrict__ Xb,
                                                  int row0, u16* dst,
                                                  int wid, int lane) {
    int kqL = lane & 31;
#pragma unroll
    for (int i = 0; i < 8; i++) {
        int t = i * 4 + wid;                   // wave-uniform instr index 0..31
        int row = 2 * t + (lane >> 5);         // 0..63
        int kqG = kqL ^ (row & 7);             // pre-swizzled source chunk
        const u16* src = (kqG < 16)
            ? agg + ((size_t)(row0 + row)) * 128 + kqG * 8
            : Xb + ((size_t)(row0 + row)) * 128 + (kqG - 16) * 8;
        gload_lds16(src, dst + (size_t)t * 512);
    }
}

// ---------------- one-shot input-dtype detection ----------------
// Runtime input-dtype detection on edge_weight (uniform [0,1)). See R4/R5 notes.
__global__ void detect_k(const void* __restrict__ ew, int* __restrict__ flag) {
    if (threadIdx.x == 0) {
        const u16* p = (const u16*)ew;
        int huge = 0, allz = 1;
        for (int i = 0; i < 128; i += 2) {
            u16 b = p[i];
            if (b != 0) allz = 0;
            float v = b2f(b);
            if (!(fabsf(v) <= 4.0f)) huge = 1;
        }
        *flag = huge | allz;
    }
}

// ---------------- node feature build (pol + tick merged) ----------------
__global__ __launch_bounds__(256) void build_x(const void* __restrict__ pf,
                                               const int* __restrict__ sid,
                                               const void* __restrict__ Wp,
                                               const void* __restrict__ bp,
                                               const void* __restrict__ semb,
                                               const void* __restrict__ et,
                                               const int* __restrict__ flag,
                                               u16* __restrict__ Xb) {
    const int f32 = *flag;
    if (blockIdx.x < N_POL / 2) {
        int row = blockIdx.x * 2 + (threadIdx.x >> 7);
        int j = threadIdx.x & 127;
        float s = lde(bp, j, f32);
#pragma unroll
        for (int k = 0; k < 7; k++)
            s = fmaf(lde(pf, (size_t)row * 7 + k, f32), lde(Wp, k * 128 + j, f32), s);
        s = fmaxf(s, 0.f);
        s += lde(semb, (size_t)sid[row] * 128 + j, f32);
        Xb[(size_t)row * 128 + j] = f2b(s);
    } else {
        int idx = (blockIdx.x - N_POL / 2) * 256 + threadIdx.x;
        Xb[(size_t)N_POL * 128 + idx] = f2b(lde(et, idx, f32));
    }
}

// ---------------- weight fragment prep (Wf1 + Wf2 merged) ----------------
// GEMM1 B[k][n]: k<128 -> W1rel[k][n], else W1root[k-128][n]; N=256.
// GEMM2 B[k][n]: n<128 -> W2rel[k][n], else W2root[k][n-128]; N=256.
__global__ __launch_bounds__(256) void prep_wf(const void* __restrict__ W1rel,
                                               const void* __restrict__ W1root,
                                               const void* __restrict__ W2rel,
                                               const void* __restrict__ W2root,
                                               const int* __restrict__ flag,
                                               u16* __restrict__ Wf1,
                                               u16* __restrict__ Wf2) {
    const int f32 = *flag;
    int idx = blockIdx.x * 256 + threadIdx.x;   // 0..131071
    int id = idx & 65535;
    int k = id >> 8, n = id & 255;
    if (idx < 65536) {
        float v = (k < 128) ? lde(W1rel, (size_t)k * 256 + n, f32)
                            : lde(W1root, (size_t)(k - 128) * 256 + n, f32);
        Wf1[frag_addr(k, n)] = f2b(v);
    } else {
        float v = (n < 128) ? lde(W2rel, (size_t)k * 128 + n, f32)
                            : lde(W2root, (size_t)k * 128 + (n - 128), f32);
        Wf2[frag_addr(k, n)] = f2b(v);
    }
}

// ---------------- CSR build ----------------
// v9: hist_dst persists the atomic's return value as the edge's rank within its
// dst. fill_csr then needs NO atomic (r9: fill_csr was fabric-atomic-bound).
__global__ __launch_bounds__(256) void hist_dst(const int* __restrict__ ei,
                                                int* __restrict__ count,
                                                int* __restrict__ rank) {
    int e = blockIdx.x * 256 + threadIdx.x;
    if (e < NEDGE) rank[e] = atomicAdd(&count[ei[NEDGE + e]], 1);
}

__global__ __launch_bounds__(256) void scan1(const int* __restrict__ count,
                                             int* __restrict__ row_tmp,
                                             int* __restrict__ bsum) {
    __shared__ int sd[256];
    int t = threadIdx.x;
    int i = blockIdx.x * 256 + t;
    int c = (i < NNODE) ? count[i] : 0;
    sd[t] = c;
    __syncthreads();
#pragma unroll
    for (int off = 1; off < 256; off <<= 1) {
        int v = (t >= off) ? sd[t - off] : 0;
        __syncthreads();
        sd[t] += v;
        __syncthreads();
    }
    if (i < NNODE) row_tmp[i] = sd[t] - c;
    if (t == 255) bsum[blockIdx.x] = sd[t];
}

__global__ __launch_bounds__(512) void scan2(int* __restrict__ bsum, int nb) {
    __shared__ int sd[512];
    int t = threadIdx.x;
    int v = (t < nb) ? bsum[t] : 0;
    sd[t] = v;
    __syncthreads();
#pragma unroll
    for (int off = 1; off < 512; off <<= 1) {
        int u = (t >= off) ? sd[t - off] : 0;
        __syncthreads();
        sd[t] += u;
        __syncthreads();
    }
    if (t < nb) bsum[t] = sd[t] - v;
}

__global__ __launch_bounds__(256) void scan3(const int* __restrict__ row_tmp,
                                             const int* __restrict__ bsum,
                                             int* __restrict__ row_start) {
    int i = blockIdx.x * 256 + threadIdx.x;
    if (i < NNODE) row_start[i] = row_tmp[i] + bsum[blockIdx.x];
    if (i == 0) row_start[NNODE] = NEDGE;
}

// fill_csr v9: atomic-free. pos = row_start[dst] + rank[e]; one packed 8B store.
__global__ __launch_bounds__(256) void fill_csr(const int* __restrict__ ei,
                                                const void* __restrict__ ew,
                                                const int* __restrict__ flag,
                                                const int* __restrict__ row_start,
                                                const int* __restrict__ rank,
                                                uint2* __restrict__ epk) {
    const int f32 = *flag;
    int e = blockIdx.x * 256 + threadIdx.x;
    if (e >= NEDGE) return;
    int src = ei[e];
    int dst = ei[NEDGE + e];
    int pos = row_start[dst] + rank[e];
    uint2 pk;
    pk.x = (unsigned)src;
    pk.y = (unsigned)f2b(lde(ew, e, f32));
    epk[pos] = pk;
}

// ---------------- gather1 (v8: packed edges; 4 edges/wave, 16B/lane) --------
__global__ __launch_bounds__(256) void gather128(const int* __restrict__ row_start,
                                                 const uint2* __restrict__ epk,
                                                 const u16* __restrict__ S,
                                                 u16* __restrict__ agg) {
    int n = blockIdx.x * 4 + (threadIdx.x >> 6);
    int lane = threadIdx.x & 63;
    int g4 = lane >> 4;        // edge slot 0..3
    int l16 = lane & 15;       // 16B chunk within the row
    int s0 = row_start[n], s1 = row_start[n + 1];
    float a[8] = {0.f, 0.f, 0.f, 0.f, 0.f, 0.f, 0.f, 0.f};
    int e = s0;
    for (; e + 8 <= s1; e += 8) {
        uint2 p0 = epk[e + g4], p1 = epk[e + 4 + g4];
        float w0 = b2f((u16)p0.y), w1 = b2f((u16)p1.y);
        ushort8 x0 = *(const ushort8*)(S + (size_t)p0.x * 128 + l16 * 8);
        ushort8 x1 = *(const ushort8*)(S + (size_t)p1.x * 128 + l16 * 8);
#pragma unroll
        for (int j = 0; j < 8; j++) {
            a[j] = fmaf(b2f(x0[j]), w0, a[j]);
            a[j] = fmaf(b2f(x1[j]), w1, a[j]);
        }
    }
    for (; e + 4 <= s1; e += 4) {
        uint2 p = epk[e + g4];
        float w = b2f((u16)p.y);
        ushort8 x = *(const ushort8*)(S + (size_t)p.x * 128 + l16 * 8);
#pragma unroll
        for (int j = 0; j < 8; j++) a[j] = fmaf(b2f(x[j]), w, a[j]);
    }
    if (e < s1) {
        int eg = e + g4;
        int valid = eg < s1;
        uint2 p = epk[valid ? eg : s0];    // s0 < s1 here, safe
        float w = valid ? b2f((u16)p.y) : 0.f;
        ushort8 x = *(const ushort8*)(S + (size_t)p.x * 128 + l16 * 8);
#pragma unroll
        for (int j = 0; j < 8; j++) a[j] = fmaf(b2f(x[j]), w, a[j]);
    }
#pragma unroll
    for (int j = 0; j < 8; j++) {
        a[j] += __shfl_xor(a[j], 16);
        a[j] += __shfl_xor(a[j], 32);
    }
    if (g4 == 0) {
        ushort8 o;
#pragma unroll
        for (int j = 0; j < 8; j++) o[j] = f2b(a[j]);
        *(ushort8*)(agg + (size_t)n * 128 + l16 * 8) = o;
    }
}

// ---------------- gather2 + add P (v8: packed edges) ----------------
__global__ __launch_bounds__(256) void gather_add(const int* __restrict__ row_start,
                                                  const uint2* __restrict__ epk,
                                                  const u16* __restrict__ T2,
                                                  const u16* __restrict__ P,
                                                  const int* __restrict__ flag,
                                                  void* __restrict__ out) {
    const int f32 = *flag;
    int n = blockIdx.x * 4 + (threadIdx.x >> 6);
    int lane = threadIdx.x & 63;
    int g4 = lane >> 4;
    int l16 = lane & 15;
    int s0 = row_start[n], s1 = row_start[n + 1];
    float a[8] = {0.f, 0.f, 0.f, 0.f, 0.f, 0.f, 0.f, 0.f};
    int e = s0;
    for (; e + 8 <= s1; e += 8) {
        uint2 p0 = epk[e + g4], p1 = epk[e + 4 + g4];
        float w0 = b2f((u16)p0.y), w1 = b2f((u16)p1.y);
        ushort8 x0 = *(const ushort8*)(T2 + (size_t)p0.x * 128 + l16 * 8);
        ushort8 x1 = *(const ushort8*)(T2 + (size_t)p1.x * 128 + l16 * 8);
#pragma unroll
        for (int j = 0; j < 8; j++) {
            a[j] = fmaf(b2f(x0[j]), w0, a[j]);
            a[j] = fmaf(b2f(x1[j]), w1, a[j]);
        }
    }
    for (; e + 4 <= s1; e += 4) {
        uint2 p = epk[e + g4];
        float w = b2f((u16)p.y);
        ushort8 x = *(const ushort8*)(T2 + (size_t)p.x * 128 + l16 * 8);
#pragma unroll
        for (int j = 0; j < 8; j++) a[j] = fmaf(b2f(x[j]), w, a[j]);
    }
    if (e < s1) {
        int eg = e + g4;
        int valid = eg < s1;
        uint2 p = epk[valid ? eg : s0];
        float w = valid ? b2f((u16)p.y) : 0.f;
        ushort8 x = *(const ushort8*)(T2 + (size_t)p.x * 128 + l16 * 8);
#pragma unroll
        for (int j = 0; j < 8; j++) a[j] = fmaf(b2f(x[j]), w, a[j]);
    }
#pragma unroll
    for (int j = 0; j < 8; j++) {
        a[j] += __shfl_xor(a[j], 16);
        a[j] += __shfl_xor(a[j], 32);
    }
    if (g4 == 0) {
        ushort8 pv = *(const ushort8*)(P + (size_t)n * 128 + l16 * 8);
        float v[8];
#pragma unroll
        for (int j = 0; j < 8; j++) v[j] = a[j] + b2f(pv[j]);
        if (f32) {
            float4 s0v, s1v;
            s0v.x = v[0]; s0v.y = v[1]; s0v.z = v[2]; s0v.w = v[3];
            s1v.x = v[4]; s1v.y = v[5]; s1v.z = v[6]; s1v.w = v[7];
            *(float4*)((float*)out + (size_t)n * 128 + l16 * 8) = s0v;
            *(float4*)((float*)out + (size_t)n * 128 + l16 * 8 + 4) = s1v;
        } else {
            ushort8 s;
#pragma unroll
            for (int j = 0; j < 8; j++) s[j] = f2b(v[j]);
            *(ushort8*)((u16*)out + (size_t)n * 128 + l16 * 8) = s;
        }
    }
}

// ---------------- fused dual MFMA GEMM (v8: multi-tile dbuf, fixed) ----------------
// Grid = 512 blocks; block b processes tiles t = b, b+512, ... (~4 tiles).
// Two 32KB buffers via POINTER SWAP (no k&1 indexing) + unroll(disable):
// r11's compiler 2x-unroll co-lived both iterations' state -> VGPR 240, occ 9.7%.
// Next-tile DMA is issued AFTER the post-phase-2 barrier (r11 issued it before;
// the compiler's vmcnt(0)-before-barrier drained it immediately = zero overlap).
// Here the out-pack (128 LDS writes + 8 reads + 8 wide stores/thread) covers the
// DMA latency; only the next loop-start barrier waits the remainder.
__global__ __launch_bounds__(256) void fused_gemm(const u16* __restrict__ agg,
                                                  const u16* __restrict__ Xb,
                                                  const u16* __restrict__ Wf1,
                                                  const u16* __restrict__ Wf2,
                                                  const void* __restrict__ b1,
                                                  const void* __restrict__ b2,
                                                  u16* __restrict__ T2,
                                                  u16* __restrict__ P,
                                                  const int* __restrict__ flag,
                                                  int ntiles) {
    const int f32 = *flag;
    __shared__ u16 LDS2[2][16384];      // 2 x 32KB: A tile -> H frags -> out tile
    const int wid = threadIdx.x >> 6;   // wave = column quarter
    const int lane = threadIdx.x & 63;
    const int q = lane >> 4, lm = lane & 15;

    u16* curB = &LDS2[0][0];
    u16* nxtB = &LDS2[1][0];

    // prologue: stage first tile
    stage_tile(agg, Xb, blockIdx.x * 64, curB, wid, lane);

#pragma clang loop unroll(disable)
    for (int t = blockIdx.x; t < ntiles; t += GB2) {
        const int row0 = t * 64;
        __syncthreads();   // drains vmcnt: curB's DMA landed; prev pack reads done

        // ---- phase 1: MFMAs only ----
        float4v acc[4][4];
#pragma unroll
        for (int i = 0; i < 4; i++)
#pragma unroll
            for (int j = 0; j < 4; j++) acc[i][j] = (float4v){0.f, 0.f, 0.f, 0.f};
#pragma unroll
        for (int kb = 0; kb < 8; kb++) {
            short8 a[4];
#pragma unroll
            for (int ti = 0; ti < 4; ti++) {
                int rl = ti * 16 + lm;
                int chunk = (kb * 4 + q) ^ (rl & 7);   // XOR-swizzle read side
                a[ti] = *(const short8*)(curB + (size_t)rl * 256 + chunk * 8);
            }
            short8 b[4];
#pragma unroll
            for (int tj = 0; tj < 4; tj++) {
                int nt = wid * 4 + tj;
                b[tj] = *(const short8*)(Wf1 + ((size_t)(nt * 8 + kb) * 64 + lane) * 8);
            }
#pragma unroll
            for (int ti = 0; ti < 4; ti++)
#pragma unroll
                for (int tj = 0; tj < 4; tj++)
                    acc[ti][tj] = __builtin_amdgcn_mfma_f32_16x16x32_bf16(
                        a[ti], b[tj], acc[ti][tj], 0, 0, 0);
        }
        __syncthreads();   // all A reads done; curB reusable for H

        // ---- phase-1 epilogue: bias + relu -> curB (phase-2 A-frag order) ----
#pragma unroll
        for (int tj = 0; tj < 4; tj++) {
            int col = wid * 64 + tj * 16 + lm;
            float bv = lde(b1, col, f32);
            int kq2 = col >> 3, jj = col & 7;
#pragma unroll
            for (int ti = 0; ti < 4; ti++) {
                int rl = ti * 16 + q * 4;
#pragma unroll
                for (int r = 0; r < 4; r++) {
                    float v = fmaxf(acc[ti][tj][r] + bv, 0.f);
                    curB[((size_t)kq2 * 64 + rl + r) * 8 + jj] = f2b(v);
                }
            }
        }
        __syncthreads();

        // ---- phase 2 ----
        float4v acc2[4][4];
#pragma unroll
        for (int i = 0; i < 4; i++)
#pragma unroll
            for (int j = 0; j < 4; j++) acc2[i][j] = (float4v){0.f, 0.f, 0.f, 0.f};
#pragma unroll
        for (int kb = 0; kb < 8; kb++) {
            short8 a[4];
#pragma unroll
            for (int ti = 0; ti < 4; ti++) {
                int rl = ti * 16 + lm;
                a[ti] = *(const short8*)(curB + ((size_t)(kb * 4 + q) * 64 + rl) * 8);
            }
            short8 b[4];
#pragma unroll
            for (int tj = 0; tj < 4; tj++) {
                int nt = wid * 4 + tj;
                b[tj] = *(const short8*)(Wf2 + ((size_t)(nt * 8 + kb) * 64 + lane) * 8);
            }
#pragma unroll
            for (int ti = 0; ti < 4; ti++)
#pragma unroll
                for (int tj = 0; tj < 4; tj++)
                    acc2[ti][tj] = __builtin_amdgcn_mfma_f32_16x16x32_bf16(
                        a[ti], b[tj], acc2[ti][tj], 0, 0, 0);
        }
        __syncthreads();   // all H reads done; curB reusable for out tile

        // issue next tile's DMA into nxtB (untouched this iteration); the pack
        // below covers its latency, next loop-start barrier drains the rest
        if (t + GB2 < ntiles)
            stage_tile(agg, Xb, (t + GB2) * 64, nxtB, wid, lane);

        // ---- phase-2 epilogue: pack [64 r][256 c] u16 tile in curB, wide stores ----
#pragma unroll
        for (int tj = 0; tj < 4; tj++) {
            int col = wid * 64 + tj * 16 + lm;
            int chunk = col >> 3, jj = col & 7;
            float bv = (col < 128) ? 0.f : lde(b2, col - 128, f32);
#pragma unroll
            for (int ti = 0; ti < 4; ti++) {
#pragma unroll
                for (int r = 0; r < 4; r++) {
                    int row = ti * 16 + q * 4 + r;
                    int pchunk = chunk ^ (((row >> 2) & 3) << 1);  // q -> bank bits
                    curB[((size_t)row * 32 + pchunk) * 8 + jj] = f2b(acc2[ti][tj][r] + bv);
                }
            }
        }
        __syncthreads();
#pragma unroll
        for (int i = 0; i < 8; i++) {
            int g = i * 256 + threadIdx.x;      // 0..2047 16B-chunks of the tile
            int row = g >> 5;                   // 0..63
            int chunk = g & 31;
            int pchunk = chunk ^ (((row >> 2) & 3) << 1);
            short8 v = *(const short8*)(curB + ((size_t)row * 32 + pchunk) * 8);
            int grow = row0 + row;
            int colu = chunk * 8;
            u16* dst = (colu < 128) ? (T2 + (size_t)grow * 128 + colu)
                                    : (P + (size_t)grow * 128 + (colu - 128));
            *(short8*)dst = v;
        }

        // swap buffers
        u16* tmp = curB; curB = nxtB; nxtB = tmp;
    }
}

extern "C" void kernel_launch(void* const* d_in, const int* in_sizes, int n_in,
                              void* d_out, int out_size, void* d_ws, size_t ws_size,
                              hipStream_t stream) {
    const void* pf     = d_in[0];
    const int*  sid    = (const int*)d_in[1];
    const int*  ei     = (const int*)d_in[2];
    const void* ew     = d_in[3];
    const void* Wp     = d_in[4];
    const void* bp     = d_in[5];
    const void* semb   = d_in[6];
    const void* et     = d_in[7];
    const void* W1rel  = d_in[8];
    const void* b1     = d_in[9];
    const void* W1root = d_in[10];
    const void* W2rel  = d_in[11];
    const void* b2     = d_in[12];
    const void* W2root = d_in[13];

    // Workspace (~106.4 MB < proven 122.88 MB budget):
    char* w = (char*)d_ws;
    u16*   agg       = (u16*)w;                    // bf16 [N,128]
    u16*   T2        = (u16*)(w + 30720000);       // bf16 [N,128]
    u16*   P         = (u16*)(w + 61440000);       // bf16 [N,128]
    u16*   Wf1       = (u16*)(w + 92160000);       // 131072 B
    u16*   Wf2       = (u16*)(w + 92291072);       // 131072 B
    uint2* epk       = (uint2*)(w + 92422144);     // packed {src,w} [E] = 8 MB
    int*   rank      = (int*)(w + 100422144);      // int [E] = 4 MB (edge rank in dst)
    int*   row_start = (int*)(w + 104422144);      // int [N+1]
    int*   row_tmp   = (int*)(w + 104902148);
    int*   count     = (int*)(w + 105382148);
    int*   bsum      = (int*)(w + 105862148);
    int*   flag      = (int*)(w + 105866244);      // dtype flag
    u16*   Xb        = (u16*)d_out;                // bf16 [N,128] scratch until fused_gemm done

    const int EB = (NEDGE + 255) / 256;   // 3907
    const int NB = (NNODE + 255) / 256;   // 469

    // one-shot dtype detection
    detect_k<<<1, 64, 0, stream>>>(ew, flag);

    // CSR build (reused by both gathers). hist_dst's atomic return = edge rank;
    // fill_csr is atomic-free (r9: fabric atomics were its bottleneck).
    hipMemsetAsync(count, 0, NNODE * sizeof(int), stream);
    hist_dst<<<EB, 256, 0, stream>>>(ei, count, rank);
    scan1<<<NB, 256, 0, stream>>>(count, row_tmp, bsum);
    scan2<<<1, 512, 0, stream>>>(bsum, NB);
    scan3<<<NB, 256, 0, stream>>>(row_tmp, bsum, row_start);
    fill_csr<<<EB, 256, 0, stream>>>(ei, ew, flag, row_start, rank, epk);

    // weight fragments (merged Wf1+Wf2)
    prep_wf<<<512, 256, 0, stream>>>(W1rel, W1root, W2rel, W2root, flag, Wf1, Wf2);

    // node features -> Xb (d_out); pol + tick merged
    build_x<<<N_POL / 2 + (N_TICK * 128) / 256, 256, 0, stream>>>(
        pf, sid, Wp, bp, semb, et, flag, Xb);

    // layer-1 aggregation
    gather128<<<NNODE / 4, 256, 0, stream>>>(row_start, epk, Xb, agg);

    // fused: H = relu([agg|Xb]@Wf1+b1) in LDS; [T2|P] = H@Wf2 (+b2 on P)
    fused_gemm<<<GB2, 256, 0, stream>>>(agg, Xb, Wf1, Wf2, b1, b2, T2, P, flag, NTILE);

    // out = P + segment_sum(w * T2)   (d_out scratch Xb is dead now)
    gather_add<<<NNODE / 4, 256, 0, stream>>>(row_start, epk, T2, P, flag, d_out);
}

// Round 13
// 373.740 us; speedup vs baseline: 1.0552x; 1.0552x over previous
//
#include <hip/hip_runtime.h>
#include <hip/hip_bf16.h>

typedef unsigned short u16;
using short8  = __attribute__((ext_vector_type(8))) short;
using ushort8 = __attribute__((ext_vector_type(8))) unsigned short;
using float4v = __attribute__((ext_vector_type(4))) float;

#define N_POL  100000
#define N_TICK 20000
#define NNODE  120000
#define NEDGE  1000000
#define NREP   8        // count replicas (keyed by blockIdx&7 ~ XCD)
// EMB=128, HID=256, OUT=128

static __device__ __forceinline__ float b2f(u16 u) {
    return __uint_as_float(((unsigned)u) << 16);
}
static __device__ __forceinline__ u16 f2b(float f) {
    unsigned u = __float_as_uint(f);
    unsigned r = (u + 0x7FFFu + ((u >> 16) & 1u)) >> 16;
    return (u16)r;
}
static __device__ __forceinline__ float lde(const void* p, size_t i, int f32) {
    return f32 ? ((const float*)p)[i] : b2f(((const u16*)p)[i]);
}

// MFMA B-fragment address for K=256, N=256 packed weights (verified R7):
// element (k,n) -> ((n/16)*8 + k/32)*512 + (((k>>3)&3)*16 + (n&15))*8 + (k&7)
static __device__ __forceinline__ size_t frag_addr(int k, int n) {
    return ((size_t)((n >> 4) * 8 + (k >> 5)) * 64 + (((k >> 3) & 3) * 16 + (n & 15))) * 8
           + (k & 7);
}

// 16B global->LDS DMA (wave-uniform LDS base; HW adds lane*16)
static __device__ __forceinline__ void gload_lds16(const u16* g, u16* l) {
    __builtin_amdgcn_global_load_lds(
        (const __attribute__((address_space(1))) void*)g,
        (__attribute__((address_space(3))) void*)l, 16, 0, 0);
}

// ---------------- one-shot input-dtype detection ----------------
// Runtime input-dtype detection on edge_weight (uniform [0,1)). See R4/R5 notes.
__global__ void detect_k(const void* __restrict__ ew, int* __restrict__ flag) {
    if (threadIdx.x == 0) {
        const u16* p = (const u16*)ew;
        int huge = 0, allz = 1;
        for (int i = 0; i < 128; i += 2) {
            u16 b = p[i];
            if (b != 0) allz = 0;
            float v = b2f(b);
            if (!(fabsf(v) <= 4.0f)) huge = 1;
        }
        *flag = huge | allz;
    }
}

// ---------------- node feature build (pol + tick merged) ----------------
__global__ __launch_bounds__(256) void build_x(const void* __restrict__ pf,
                                               const int* __restrict__ sid,
                                               const void* __restrict__ Wp,
                                               const void* __restrict__ bp,
                                               const void* __restrict__ semb,
                                               const void* __restrict__ et,
                                               const int* __restrict__ flag,
                                               u16* __restrict__ Xb) {
    const int f32 = *flag;
    if (blockIdx.x < N_POL / 2) {
        int row = blockIdx.x * 2 + (threadIdx.x >> 7);
        int j = threadIdx.x & 127;
        float s = lde(bp, j, f32);
#pragma unroll
        for (int k = 0; k < 7; k++)
            s = fmaf(lde(pf, (size_t)row * 7 + k, f32), lde(Wp, k * 128 + j, f32), s);
        s = fmaxf(s, 0.f);
        s += lde(semb, (size_t)sid[row] * 128 + j, f32);
        Xb[(size_t)row * 128 + j] = f2b(s);
    } else {
        int idx = (blockIdx.x - N_POL / 2) * 256 + threadIdx.x;
        Xb[(size_t)N_POL * 128 + idx] = f2b(lde(et, idx, f32));
    }
}

// ---------------- weight fragment prep (Wf1 + Wf2 merged) ----------------
// GEMM1 B[k][n]: k<128 -> W1rel[k][n], else W1root[k-128][n]; N=256.
// GEMM2 B[k][n]: n<128 -> W2rel[k][n], else W2root[k][n-128]; N=256.
__global__ __launch_bounds__(256) void prep_wf(const void* __restrict__ W1rel,
                                               const void* __restrict__ W1root,
                                               const void* __restrict__ W2rel,
                                               const void* __restrict__ W2root,
                                               const int* __restrict__ flag,
                                               u16* __restrict__ Wf1,
                                               u16* __restrict__ Wf2) {
    const int f32 = *flag;
    int idx = blockIdx.x * 256 + threadIdx.x;   // 0..131071
    int id = idx & 65535;
    int k = id >> 8, n = id & 255;
    if (idx < 65536) {
        float v = (k < 128) ? lde(W1rel, (size_t)k * 256 + n, f32)
                            : lde(W1root, (size_t)(k - 128) * 256 + n, f32);
        Wf1[frag_addr(k, n)] = f2b(v);
    } else {
        float v = (n < 128) ? lde(W2rel, (size_t)k * 128 + n, f32)
                            : lde(W2root, (size_t)k * 128 + (n - 128), f32);
        Wf2[frag_addr(k, n)] = f2b(v);
    }
}

// ---------------- CSR build ----------------
// v10: 8-way replicated count keyed by blockIdx&7 (~XCD under round-robin
// dispatch). r8/r9: 1M device-scope atomics on a shared 480KB count array cost
// ~60-77us (cross-XCD line ping-pong: ~133 increments/line from all 8 XCDs).
// Replication makes most atomic traffic XCD-local. Ranks stay globally unique:
// slot = row_start[dst] + roff[rep][dst] + rank_local, roff = per-node prefix
// over replicas (computed in scan1). Gathers sum => order irrelevant.
__global__ __launch_bounds__(256) void hist_dst(const int* __restrict__ ei,
                                                int* __restrict__ count,
                                                int* __restrict__ rank) {
    int rep = blockIdx.x & (NREP - 1);
    int e = blockIdx.x * 256 + threadIdx.x;
    if (e < NEDGE)
        rank[e] = atomicAdd(&count[rep * NNODE + ei[NEDGE + e]], 1);
}

__global__ __launch_bounds__(256) void scan1(const int* __restrict__ count,
                                             int* __restrict__ roff,
                                             int* __restrict__ row_tmp,
                                             int* __restrict__ bsum) {
    __shared__ int sd[256];
    int t = threadIdx.x;
    int i = blockIdx.x * 256 + t;
    int c = 0;
    if (i < NNODE) {
#pragma unroll
        for (int r = 0; r < NREP; r++) {
            int v = count[r * NNODE + i];
            roff[r * NNODE + i] = c;     // prefix over replicas for this node
            c += v;
        }
    }
    sd[t] = c;
    __syncthreads();
#pragma unroll
    for (int off = 1; off < 256; off <<= 1) {
        int v = (t >= off) ? sd[t - off] : 0;
        __syncthreads();
        sd[t] += v;
        __syncthreads();
    }
    if (i < NNODE) row_tmp[i] = sd[t] - c;
    if (t == 255) bsum[blockIdx.x] = sd[t];
}

__global__ __launch_bounds__(512) void scan2(int* __restrict__ bsum, int nb) {
    __shared__ int sd[512];
    int t = threadIdx.x;
    int v = (t < nb) ? bsum[t] : 0;
    sd[t] = v;
    __syncthreads();
#pragma unroll
    for (int off = 1; off < 512; off <<= 1) {
        int u = (t >= off) ? sd[t - off] : 0;
        __syncthreads();
        sd[t] += u;
        __syncthreads();
    }
    if (t < nb) bsum[t] = sd[t] - v;
}

__global__ __launch_bounds__(256) void scan3(const int* __restrict__ row_tmp,
                                             const int* __restrict__ bsum,
                                             int* __restrict__ row_start) {
    int i = blockIdx.x * 256 + threadIdx.x;
    if (i < NNODE) row_start[i] = row_tmp[i] + bsum[blockIdx.x];
    if (i == 0) row_start[NNODE] = NEDGE;
}

// fill_csr: atomic-free. pos = row_start[dst] + roff[rep][dst] + rank[e].
// roff load is random 4B but the 3.84MB region is L2-resident.
__global__ __launch_bounds__(256) void fill_csr(const int* __restrict__ ei,
                                                const void* __restrict__ ew,
                                                const int* __restrict__ flag,
                                                const int* __restrict__ row_start,
                                                const int* __restrict__ roff,
                                                const int* __restrict__ rank,
                                                uint2* __restrict__ epk) {
    const int f32 = *flag;
    int rep = blockIdx.x & (NREP - 1);
    int e = blockIdx.x * 256 + threadIdx.x;
    if (e >= NEDGE) return;
    int src = ei[e];
    int dst = ei[NEDGE + e];
    int pos = row_start[dst] + roff[rep * NNODE + dst] + rank[e];
    uint2 pk;
    pk.x = (unsigned)src;
    pk.y = (unsigned)f2b(lde(ew, e, f32));
    epk[pos] = pk;
}

// ---------------- gather1 (v8: packed edges; 4 edges/wave, 16B/lane) --------
__global__ __launch_bounds__(256) void gather128(const int* __restrict__ row_start,
                                                 const uint2* __restrict__ epk,
                                                 const u16* __restrict__ S,
                                                 u16* __restrict__ agg) {
    int n = blockIdx.x * 4 + (threadIdx.x >> 6);
    int lane = threadIdx.x & 63;
    int g4 = lane >> 4;        // edge slot 0..3
    int l16 = lane & 15;       // 16B chunk within the row
    int s0 = row_start[n], s1 = row_start[n + 1];
    float a[8] = {0.f, 0.f, 0.f, 0.f, 0.f, 0.f, 0.f, 0.f};
    int e = s0;
    for (; e + 8 <= s1; e += 8) {
        uint2 p0 = epk[e + g4], p1 = epk[e + 4 + g4];
        float w0 = b2f((u16)p0.y), w1 = b2f((u16)p1.y);
        ushort8 x0 = *(const ushort8*)(S + (size_t)p0.x * 128 + l16 * 8);
        ushort8 x1 = *(const ushort8*)(S + (size_t)p1.x * 128 + l16 * 8);
#pragma unroll
        for (int j = 0; j < 8; j++) {
            a[j] = fmaf(b2f(x0[j]), w0, a[j]);
            a[j] = fmaf(b2f(x1[j]), w1, a[j]);
        }
    }
    for (; e + 4 <= s1; e += 4) {
        uint2 p = epk[e + g4];
        float w = b2f((u16)p.y);
        ushort8 x = *(const ushort8*)(S + (size_t)p.x * 128 + l16 * 8);
#pragma unroll
        for (int j = 0; j < 8; j++) a[j] = fmaf(b2f(x[j]), w, a[j]);
    }
    if (e < s1) {
        int eg = e + g4;
        int valid = eg < s1;
        uint2 p = epk[valid ? eg : s0];    // s0 < s1 here, safe
        float w = valid ? b2f((u16)p.y) : 0.f;
        ushort8 x = *(const ushort8*)(S + (size_t)p.x * 128 + l16 * 8);
#pragma unroll
        for (int j = 0; j < 8; j++) a[j] = fmaf(b2f(x[j]), w, a[j]);
    }
#pragma unroll
    for (int j = 0; j < 8; j++) {
        a[j] += __shfl_xor(a[j], 16);
        a[j] += __shfl_xor(a[j], 32);
    }
    if (g4 == 0) {
        ushort8 o;
#pragma unroll
        for (int j = 0; j < 8; j++) o[j] = f2b(a[j]);
        *(ushort8*)(agg + (size_t)n * 128 + l16 * 8) = o;
    }
}

// ---------------- gather2 + add P (v8: packed edges) ----------------
__global__ __launch_bounds__(256) void gather_add(const int* __restrict__ row_start,
                                                  const uint2* __restrict__ epk,
                                                  const u16* __restrict__ T2,
                                                  const u16* __restrict__ P,
                                                  const int* __restrict__ flag,
                                                  void* __restrict__ out) {
    const int f32 = *flag;
    int n = blockIdx.x * 4 + (threadIdx.x >> 6);
    int lane = threadIdx.x & 63;
    int g4 = lane >> 4;
    int l16 = lane & 15;
    int s0 = row_start[n], s1 = row_start[n + 1];
    float a[8] = {0.f, 0.f, 0.f, 0.f, 0.f, 0.f, 0.f, 0.f};
    int e = s0;
    for (; e + 8 <= s1; e += 8) {
        uint2 p0 = epk[e + g4], p1 = epk[e + 4 + g4];
        float w0 = b2f((u16)p0.y), w1 = b2f((u16)p1.y);
        ushort8 x0 = *(const ushort8*)(T2 + (size_t)p0.x * 128 + l16 * 8);
        ushort8 x1 = *(const ushort8*)(T2 + (size_t)p1.x * 128 + l16 * 8);
#pragma unroll
        for (int j = 0; j < 8; j++) {
            a[j] = fmaf(b2f(x0[j]), w0, a[j]);
            a[j] = fmaf(b2f(x1[j]), w1, a[j]);
        }
    }
    for (; e + 4 <= s1; e += 4) {
        uint2 p = epk[e + g4];
        float w = b2f((u16)p.y);
        ushort8 x = *(const ushort8*)(T2 + (size_t)p.x * 128 + l16 * 8);
#pragma unroll
        for (int j = 0; j < 8; j++) a[j] = fmaf(b2f(x[j]), w, a[j]);
    }
    if (e < s1) {
        int eg = e + g4;
        int valid = eg < s1;
        uint2 p = epk[valid ? eg : s0];
        float w = valid ? b2f((u16)p.y) : 0.f;
        ushort8 x = *(const ushort8*)(T2 + (size_t)p.x * 128 + l16 * 8);
#pragma unroll
        for (int j = 0; j < 8; j++) a[j] = fmaf(b2f(x[j]), w, a[j]);
    }
#pragma unroll
    for (int j = 0; j < 8; j++) {
        a[j] += __shfl_xor(a[j], 16);
        a[j] += __shfl_xor(a[j], 32);
    }
    if (g4 == 0) {
        ushort8 pv = *(const ushort8*)(P + (size_t)n * 128 + l16 * 8);
        float v[8];
#pragma unroll
        for (int j = 0; j < 8; j++) v[j] = a[j] + b2f(pv[j]);
        if (f32) {
            float4 s0v, s1v;
            s0v.x = v[0]; s0v.y = v[1]; s0v.z = v[2]; s0v.w = v[3];
            s1v.x = v[4]; s1v.y = v[5]; s1v.z = v[6]; s1v.w = v[7];
            *(float4*)((float*)out + (size_t)n * 128 + l16 * 8) = s0v;
            *(float4*)((float*)out + (size_t)n * 128 + l16 * 8 + 4) = s1v;
        } else {
            ushort8 s;
#pragma unroll
            for (int j = 0; j < 8; j++) s[j] = f2b(v[j]);
            *(ushort8*)((u16*)out + (size_t)n * 128 + l16 * 8) = s;
        }
    }
}

// ---------------- fused dual MFMA GEMM (v6 REVERT: single-tile, known 66.4us) -----
// r11/r12 multi-tile dbuf both hit VGPR 240 / occ 9.7% (compiler pipelines the
// tile loop regardless of unroll pragmas) -> kill-switch: back to v6.
// Phase 1: H = relu([agg|Xb] @ Wf1 + b1)   (64 rows x 256 cols)
// Phase 2: [T2 | P] = H @ Wf2 (+b2 on P half)
// Block 256 thr = 4 waves side-by-side in columns; acc[4][4] = 64 regs/phase.
// LDSU (32 KB): A tile (XOR-swizzled, linear-dest DMA) -> H frags -> out tile.
// Epilogue-2: pack u16 tile in LDS (swizzled), then 8 coalesced 16B stores/thread.
__global__ __launch_bounds__(256) void fused_gemm(const u16* __restrict__ agg,
                                                  const u16* __restrict__ Xb,
                                                  const u16* __restrict__ Wf1,
                                                  const u16* __restrict__ Wf2,
                                                  const void* __restrict__ b1,
                                                  const void* __restrict__ b2,
                                                  u16* __restrict__ T2,
                                                  u16* __restrict__ P,
                                                  const int* __restrict__ flag,
                                                  int M) {
    const int f32 = *flag;
    __shared__ u16 LDSU[32 * 64 * 8];   // 32 KB: A tile -> H frags -> out tile
    const int row0 = blockIdx.x * 64;
    const int wid = threadIdx.x >> 6;   // wave = column quarter
    const int lane = threadIdx.x & 63;
    const int q = lane >> 4, lm = lane & 15;

    // ---- stage A tile (64 rows x K=256: chunks 0-15 agg, 16-31 Xb) ----
    {
        int kqL = lane & 31;
#pragma unroll
        for (int i = 0; i < 8; i++) {
            int t = i * 4 + wid;                   // wave-uniform instr index 0..31
            int row = 2 * t + (lane >> 5);         // 0..63
            int kqG = kqL ^ (row & 7);             // pre-swizzled source chunk
            const u16* src = (kqG < 16)
                ? agg + ((size_t)(row0 + row)) * 128 + kqG * 8
                : Xb + ((size_t)(row0 + row)) * 128 + (kqG - 16) * 8;
            gload_lds16(src, LDSU + (size_t)t * 512);
        }
    }
    __syncthreads();   // drains vmcnt (global_load_lds) before any ds_read

    // ---- phase 1: MFMAs only (epilogue deferred so LDSU can be reused) ----
    float4v acc[4][4];   // [ti rows][tj cols]
#pragma unroll
    for (int i = 0; i < 4; i++)
#pragma unroll
        for (int j = 0; j < 4; j++) acc[i][j] = (float4v){0.f, 0.f, 0.f, 0.f};
#pragma unroll
    for (int kb = 0; kb < 8; kb++) {
        short8 a[4];
#pragma unroll
        for (int ti = 0; ti < 4; ti++) {
            int rl = ti * 16 + lm;
            int chunk = (kb * 4 + q) ^ (rl & 7);   // XOR-swizzle read side
            a[ti] = *(const short8*)(LDSU + (size_t)rl * 256 + chunk * 8);
        }
        short8 b[4];
#pragma unroll
        for (int tj = 0; tj < 4; tj++) {
            int nt = wid * 4 + tj;
            b[tj] = *(const short8*)(Wf1 + ((size_t)(nt * 8 + kb) * 64 + lane) * 8);
        }
#pragma unroll
        for (int ti = 0; ti < 4; ti++)
#pragma unroll
            for (int tj = 0; tj < 4; tj++)
                acc[ti][tj] = __builtin_amdgcn_mfma_f32_16x16x32_bf16(
                    a[ti], b[tj], acc[ti][tj], 0, 0, 0);
    }
    __syncthreads();   // all A reads done; LDSU now reusable for H

    // ---- phase-1 epilogue: bias + relu -> LDSU (phase-2 A-frag order) ----
#pragma unroll
    for (int tj = 0; tj < 4; tj++) {
        int col = wid * 64 + tj * 16 + lm;
        float bv = lde(b1, col, f32);
        int kq2 = col >> 3, jj = col & 7;
#pragma unroll
        for (int ti = 0; ti < 4; ti++) {
            int rl = ti * 16 + q * 4;
#pragma unroll
            for (int r = 0; r < 4; r++) {
                float v = fmaxf(acc[ti][tj][r] + bv, 0.f);
                LDSU[((size_t)kq2 * 64 + rl + r) * 8 + jj] = f2b(v);
            }
        }
    }
    __syncthreads();

    // ---- phase 2 ----
    float4v acc2[4][4];
#pragma unroll
    for (int i = 0; i < 4; i++)
#pragma unroll
        for (int j = 0; j < 4; j++) acc2[i][j] = (float4v){0.f, 0.f, 0.f, 0.f};
#pragma unroll
    for (int kb = 0; kb < 8; kb++) {
        short8 a[4];
#pragma unroll
        for (int ti = 0; ti < 4; ti++) {
            int rl = ti * 16 + lm;
            a[ti] = *(const short8*)(LDSU + ((size_t)(kb * 4 + q) * 64 + rl) * 8);
        }
        short8 b[4];
#pragma unroll
        for (int tj = 0; tj < 4; tj++) {
            int nt = wid * 4 + tj;
            b[tj] = *(const short8*)(Wf2 + ((size_t)(nt * 8 + kb) * 64 + lane) * 8);
        }
#pragma unroll
        for (int ti = 0; ti < 4; ti++)
#pragma unroll
            for (int tj = 0; tj < 4; tj++)
                acc2[ti][tj] = __builtin_amdgcn_mfma_f32_16x16x32_bf16(
                    a[ti], b[tj], acc2[ti][tj], 0, 0, 0);
    }
    __syncthreads();   // all H reads done; LDSU now reusable for output tile

    // ---- phase-2 epilogue: pack [64 r][256 c] u16 tile in LDS, then wide stores ----
#pragma unroll
    for (int tj = 0; tj < 4; tj++) {
        int col = wid * 64 + tj * 16 + lm;
        int chunk = col >> 3, jj = col & 7;
        float bv = (col < 128) ? 0.f : lde(b2, col - 128, f32);
#pragma unroll
        for (int ti = 0; ti < 4; ti++) {
#pragma unroll
            for (int r = 0; r < 4; r++) {
                int row = ti * 16 + q * 4 + r;
                int pchunk = chunk ^ (((row >> 2) & 3) << 1);  // q -> bank bits
                LDSU[((size_t)row * 32 + pchunk) * 8 + jj] = f2b(acc2[ti][tj][r] + bv);
            }
        }
    }
    __syncthreads();
#pragma unroll
    for (int i = 0; i < 8; i++) {
        int g = i * 256 + threadIdx.x;      // 0..2047 16B-chunks of the tile
        int row = g >> 5;                   // 0..63
        int chunk = g & 31;
        int pchunk = chunk ^ (((row >> 2) & 3) << 1);
        short8 v = *(const short8*)(LDSU + ((size_t)row * 32 + pchunk) * 8);
        int grow = row0 + row;
        int colu = chunk * 8;
        u16* dst = (colu < 128) ? (T2 + (size_t)grow * 128 + colu)
                                : (P + (size_t)grow * 128 + (colu - 128));
        *(short8*)dst = v;
    }
    (void)M;
}

extern "C" void kernel_launch(void* const* d_in, const int* in_sizes, int n_in,
                              void* d_out, int out_size, void* d_ws, size_t ws_size,
                              hipStream_t stream) {
    const void* pf     = d_in[0];
    const int*  sid    = (const int*)d_in[1];
    const int*  ei     = (const int*)d_in[2];
    const void* ew     = d_in[3];
    const void* Wp     = d_in[4];
    const void* bp     = d_in[5];
    const void* semb   = d_in[6];
    const void* et     = d_in[7];
    const void* W1rel  = d_in[8];
    const void* b1     = d_in[9];
    const void* W1root = d_in[10];
    const void* W2rel  = d_in[11];
    const void* b2     = d_in[12];
    const void* W2root = d_in[13];

    // Workspace (~113.1 MB < proven 122.88 MB budget):
    char* w = (char*)d_ws;
    u16*   agg       = (u16*)w;                    // bf16 [N,128]
    u16*   T2        = (u16*)(w + 30720000);       // bf16 [N,128]
    u16*   P         = (u16*)(w + 61440000);       // bf16 [N,128]
    u16*   Wf1       = (u16*)(w + 92160000);       // 131072 B
    u16*   Wf2       = (u16*)(w + 92291072);       // 131072 B
    uint2* epk       = (uint2*)(w + 92422144);     // packed {src,w} [E] = 8 MB
    int*   rank      = (int*)(w + 100422144);      // int [E] = 4 MB
    int*   row_start = (int*)(w + 104422144);      // int [N+1]
    int*   row_tmp   = (int*)(w + 104902148);      // int [N]
    int*   count     = (int*)(w + 105382148);      // int [NREP][N] = 3.84 MB
    int*   roff      = (int*)(w + 109222148);      // int [NREP][N] = 3.84 MB
    int*   bsum      = (int*)(w + 113062148);      // int [512]
    int*   flag      = (int*)(w + 113066244);      // dtype flag
    u16*   Xb        = (u16*)d_out;                // bf16 [N,128] scratch until fused_gemm done

    const int EB = (NEDGE + 255) / 256;   // 3907
    const int NB = (NNODE + 255) / 256;   // 469
    const int GB = (NNODE + 63) / 64;     // 1875

    // one-shot dtype detection
    detect_k<<<1, 64, 0, stream>>>(ew, flag);

    // CSR build. hist_dst: 8-way replicated count (XCD-local atomics);
    // fill_csr atomic-free via rank + per-node replica offsets.
    hipMemsetAsync(count, 0, NREP * NNODE * sizeof(int), stream);
    hist_dst<<<EB, 256, 0, stream>>>(ei, count, rank);
    scan1<<<NB, 256, 0, stream>>>(count, roff, row_tmp, bsum);
    scan2<<<1, 512, 0, stream>>>(bsum, NB);
    scan3<<<NB, 256, 0, stream>>>(row_tmp, bsum, row_start);
    fill_csr<<<EB, 256, 0, stream>>>(ei, ew, flag, row_start, roff, rank, epk);

    // weight fragments (merged Wf1+Wf2)
    prep_wf<<<512, 256, 0, stream>>>(W1rel, W1root, W2rel, W2root, flag, Wf1, Wf2);

    // node features -> Xb (d_out); pol + tick merged
    build_x<<<N_POL / 2 + (N_TICK * 128) / 256, 256, 0, stream>>>(
        pf, sid, Wp, bp, semb, et, flag, Xb);

    // layer-1 aggregation
    gather128<<<NNODE / 4, 256, 0, stream>>>(row_start, epk, Xb, agg);

    // fused: H = relu([agg|Xb]@Wf1+b1) in LDS; [T2|P] = H@Wf2 (+b2 on P)
    fused_gemm<<<GB, 256, 0, stream>>>(agg, Xb, Wf1, Wf2, b1, b2, T2, P, flag, NNODE);

    // out = P + segment_sum(w * T2)   (d_out scratch Xb is dead now)
    gather_add<<<NNODE / 4, 256, 0, stream>>>(row_start, epk, T2, P, flag, d_out);
}